// Round 1
// baseline (1070.692 us; speedup 1.0000x reference)
//
#include <hip/hip_runtime.h>
#include <math.h>

typedef __attribute__((ext_vector_type(8))) short bf16x8;
typedef __attribute__((ext_vector_type(4))) float f32x4;

namespace {
constexpr int BB = 8, CH = 128, KC = 64, HWD = 65536;
constexpr int TILE = 64;                 // px per tile
constexpr int TPB  = 256;                // 4 waves
constexpr int TILES_PER_BLOCK = 16;      // 1024 px per block
constexpr int PX_PER_BLOCK = TILE * TILES_PER_BLOCK;
constexpr int BLOCKS_PER_B = HWD / PX_PER_BLOCK;   // 64
constexpr int TILE_BYTES = 16384;        // 64px x 128c x 2B packed bf16 tile

// workspace float offsets
constexpr int OFF_SUMS  = 0;                     // [8][64][128]
constexpr int OFF_CNT   = OFF_SUMS + BB*KC*CH;   // [8][64]
constexpr int OFF_CHSQ  = OFF_CNT + BB*KC;       // [128]
constexpr int OFF_AM    = OFF_CHSQ + CH;         // [8][64][128]
constexpr int OFF_SCALE = OFF_AM + BB*KC*CH;     // [128]
constexpr int OFF_BIAS  = OFF_SCALE + CH;        // [128]
constexpr int OFF_AMSB  = OFF_BIAS + CH;         // [8][64][128] am*sc+bi
// packed x tiles: [b][pxblk(1024)][cc(8)][64px][16c] bf16, slot-swizzled.
// 134,217,728 bytes. OFF_XP*4 = 790016 B (16B aligned).
constexpr int OFF_XP    = OFF_AMSB + BB*KC*CH;
}

__device__ __forceinline__ short f2bf(float f) {   // RNE fp32->bf16
  unsigned u = __builtin_bit_cast(unsigned, f);
  u += 0x7fffu + ((u >> 16) & 1u);
  return (short)(u >> 16);
}

// async 16B global->LDS DMA (lane-linear dest: wave-uniform base + lane*16)
__device__ __forceinline__ void gload_lds16(const void* g, void* l) {
  __builtin_amdgcn_global_load_lds(
      (const __attribute__((address_space(1))) unsigned*)g,
      (__attribute__((address_space(3))) unsigned*)l, 16, 0, 0);
}

// Stage one packed 16KB tile into LDS: 16 x 1KB chunks, 4 per wave.
// Global side carries lane*16; LDS side is the wave-uniform chunk base.
__device__ __forceinline__ void stage_tile(const char* __restrict__ gsrc,
                                           short* __restrict__ dst,
                                           int w, int lane) {
#pragma unroll
  for (int i = 0; i < 4; ++i) {
    const int c = (w * 4 + i) * 1024;
    gload_lds16(gsrc + c + lane * 16, (char*)dst + c);
  }
}

// B-fragment read from the packed/swizzled LDS tile image.
// Layout: [cc(8)][px(64)][2 slots of 16B]; slot = octant(c) ^ (px>>2 & 1).
// c = kc*32 + quad*8 + j  ->  cc = kc*2 + (quad>>1), octant = quad&1.
// Bank-balanced for wave64 b128 (8 lanes/bank = minimum) -> conflict-free.
__device__ __forceinline__ bf16x8 bfrag(const char* __restrict__ xt,
                                        int pxl, int kc, int quad) {
  const int cc   = kc * 2 + (quad >> 1);
  const int slot = (quad & 1) ^ ((pxl >> 2) & 1);
  return *(const bf16x8*)(xt + cc * 2048 + pxl * 32 + (slot << 4));
}

// A-operand (weight^T) fragments held in registers for the whole kernel.
__device__ __forceinline__ void load_w_frags(const float* __restrict__ w,
                                             int mbase, int lane15, int quad,
                                             bf16x8 af[4][4]) {
#pragma unroll
  for (int mt = 0; mt < 4; ++mt) {
    const int d = mbase + mt * 16 + lane15;
#pragma unroll
    for (int kc = 0; kc < 4; ++kc) {
      const int c0 = kc * 32 + quad * 8;
      bf16x8 f;
#pragma unroll
      for (int j = 0; j < 8; ++j) f[j] = f2bf(w[(size_t)(c0 + j) * CH + d]);
      af[mt][kc] = f;
    }
  }
}

// ---------------------------------------------------------------------------
// K0: pack x (fp32 [b][c][px], 2^18-strided rows) into bf16 tiles
// xp[b][pxblk][cc][64px][16c] (16KB contiguous per tile, swizzle baked in).
// Reads: 2KB contiguous runs per row per wave (DRAM-page friendly).
// Writes: 16B granules, each 2KB chunk fully written by one block -> L2 merge.
// ---------------------------------------------------------------------------
__global__ __launch_bounds__(TPB) void k0_pack(const float* __restrict__ x,
                                               float* __restrict__ ws)
{
  char* xp = (char*)(ws + OFF_XP);
  const int blk = blockIdx.x;
  const int b   = blk >> 8;            // 256 blocks per batch
  const int pg  = (blk >> 2) & 63;     // 1024-px group
  const int cc0 = (blk & 3) * 2;       // this block does 2 of 8 c-chunks
  const int t = threadIdx.x;
  const int o = t >> 7;                // c-octant within 16-c chunk (0/1)
  const int g = t & 127;               // 8-px group
  const int px0 = pg * PX_PER_BLOCK;
  const float* xb = x + (size_t)b * CH * HWD;

#pragma unroll
  for (int cci = 0; cci < 2; ++cci) {
    const int cc = cc0 + cci;
    float4 v[8][2];
#pragma unroll
    for (int r = 0; r < 8; ++r) {
      const float* row = &xb[(size_t)(cc * 16 + o * 8 + r) * HWD + px0 + g * 8];
      v[r][0] = *(const float4*)row;
      v[r][1] = *(const float4*)(row + 4);
    }
#pragma unroll
    for (int k = 0; k < 8; ++k) {
      bf16x8 wv;
#pragma unroll
      for (int r = 0; r < 8; ++r)
        wv[r] = f2bf(((const float*)&v[r][k >> 2])[k & 3]);
      const int px = px0 + g * 8 + k;
      const size_t ti = (size_t)b * 1024 + (px >> 6);
      const int slot = o ^ ((px >> 2) & 1);
      *(bf16x8*)(xp + ti * TILE_BYTES + cc * 2048 + (px & 63) * 32 + (slot << 4)) = wv;
    }
  }
}

// ---------------------------------------------------------------------------
// K1: MFMA xw tile from packed xp (global_load_lds, double-buffered);
// accumulate per-(b,class) sums (LDS atomics), counts, per-lane sum(xw^2).
// ---------------------------------------------------------------------------
__global__ __launch_bounds__(TPB) void k1_mfma(
    const int* __restrict__ index,
    const float* __restrict__ weight, float* __restrict__ ws)
{
  __shared__ short xs[2][TILE_BYTES / 2];      // 2 x 16KB packed tile
  __shared__ float csum[KC][CH + 1];           // 33 KB, bank=(cls+d)%32
  __shared__ float ccnt[KC];
  __shared__ float chsq_s[CH];

  const int t = threadIdx.x;
  const int lane = t & 63, lane15 = lane & 15, quad = lane >> 4, w = t >> 6;
  const int mbase = (w & 1) * 64;              // d-half owned by this wave
  const int nbase = (w >> 1) * 32;             // px-half owned by this wave
  const int b = blockIdx.x / BLOCKS_PER_B;
  const int px_base = (blockIdx.x % BLOCKS_PER_B) * PX_PER_BLOCK;
  const size_t ti0 = (size_t)b * 1024 + (px_base >> 6);
  const char* xp = (const char*)(ws + OFF_XP);

  for (int i = t; i < KC * (CH + 1); i += TPB) (&csum[0][0])[i] = 0.f;
  if (t < KC) ccnt[t] = 0.f;
  if (t < CH) chsq_s[t] = 0.f;

  bf16x8 af[4][4];
  load_w_frags(weight, mbase, lane15, quad, af);

  float sq[4][4] = {};
  const int* ib = index + (size_t)b * HWD;

  stage_tile(xp + ti0 * TILE_BYTES, &xs[0][0], w, lane);
  __syncthreads();   // covers csum zero-fill + tile0 DMA

  for (int tile = 0; tile < TILES_PER_BLOCK; ++tile) {
    const int cur = tile & 1;
    if (tile + 1 < TILES_PER_BLOCK)
      stage_tile(xp + (ti0 + tile + 1) * TILE_BYTES, &xs[cur ^ 1][0], w, lane);

    const int pix0 = px_base + tile * TILE;
    int cls[2];
#pragma unroll
    for (int nt = 0; nt < 2; ++nt) cls[nt] = ib[pix0 + nbase + nt * 16 + lane15];

    const char* xt = (const char*)&xs[cur][0];
    f32x4 acc[4][2] = {};
#pragma unroll
    for (int kc = 0; kc < 4; ++kc) {
      bf16x8 bfr[2];
#pragma unroll
      for (int nt = 0; nt < 2; ++nt)
        bfr[nt] = bfrag(xt, nbase + nt * 16 + lane15, kc, quad);
#pragma unroll
      for (int mt = 0; mt < 4; ++mt)
#pragma unroll
        for (int nt = 0; nt < 2; ++nt)
          acc[mt][nt] = __builtin_amdgcn_mfma_f32_16x16x32_bf16(af[mt][kc], bfr[nt], acc[mt][nt], 0, 0, 0);
    }

    // D layout: lane px = lane&15 (+tile base), d = mbase+mt*16+quad*4+r
#pragma unroll
    for (int nt = 0; nt < 2; ++nt) {
      float* cr = &csum[cls[nt]][0];
#pragma unroll
      for (int mt = 0; mt < 4; ++mt)
#pragma unroll
        for (int r = 0; r < 4; ++r) {
          const float v = acc[mt][nt][r];
          atomicAdd(&cr[mbase + mt * 16 + quad * 4 + r], v);
          sq[mt][r] += v * v;
        }
    }
    if ((w & 1) == 0 && lane < 16) {   // one wave per px-half, quad 0 only
      atomicAdd(&ccnt[cls[0]], 1.f);
      atomicAdd(&ccnt[cls[1]], 1.f);
    }
    __syncthreads();   // drains next-tile DMA + finishes xs[cur] reads
  }

  // flush block-local accumulators (rotated to decorrelate atomic hot lines)
  float* sums_g = ws + OFF_SUMS + (size_t)b * KC * CH;
  const int rot = (blockIdx.x & 63) * 131;
  for (int i = t; i < KC * CH; i += TPB) {
    const int ii = (i + rot) & (KC * CH - 1);
    atomicAdd(&sums_g[ii], csum[ii >> 7][ii & 127]);
  }
#pragma unroll
  for (int mt = 0; mt < 4; ++mt)
#pragma unroll
    for (int r = 0; r < 4; ++r)
      atomicAdd(&chsq_s[mbase + mt * 16 + quad * 4 + r], sq[mt][r]);
  __syncthreads();
  if (t < KC) atomicAdd(&ws[OFF_CNT + b * KC + t], ccnt[t]);
  if (t < CH) atomicAdd(&ws[OFF_CHSQ + t], chsq_s[t]);
}

// ---------------------------------------------------------------------------
// K2: per-batch means, Y = means@W, quad = |Y_p - Y_q|^2, adjacency,
// adj_means = adj_nd @ means. One block per batch. (unchanged, ~µs)
// ---------------------------------------------------------------------------
__global__ __launch_bounds__(TPB) void k2_adj(
    const float* __restrict__ Wm, const float* __restrict__ adj_mask,
    float* __restrict__ ws)
{
  __shared__ float ms[KC][CH + 1];
  __shared__ float Ys[KC][CH + 1];
  __shared__ float wm[KC][KC];
  __shared__ float yy[KC];
  const int b = blockIdx.x, t = threadIdx.x;
  const float* sums = ws + OFF_SUMS + (size_t)b * KC * CH;
  const float* cnt  = ws + OFF_CNT + b * KC;

  for (int i = t; i < KC * CH; i += TPB) {
    const int k = i >> 7, d = i & 127;
    const float c = cnt[k];
    ms[k][d] = sums[i] / (c == 0.f ? 1.f : c);
  }
  __syncthreads();
  for (int i = t; i < KC * CH; i += TPB) {
    const int k = i >> 7, e = i & 127;
    float a = 0.f;
    for (int c = 0; c < CH; ++c) a += ms[k][c] * Wm[c * CH + e];
    Ys[k][e] = a;
  }
  __syncthreads();
  if (t < KC) {
    float a = 0.f;
    for (int e = 0; e < CH; ++e) { const float v = Ys[t][e]; a += v * v; }
    yy[t] = a;
  }
  __syncthreads();
  for (int i = t; i < KC * KC; i += TPB) {
    const int p = i >> 6, q = i & 63;
    float g = 0.f;
    for (int e = 0; e < CH; ++e) g += Ys[p][e] * Ys[q][e];
    const float quad = yy[p] + yy[q] - 2.f * g;
    wm[p][q] = (p == q) ? 0.f : expf(-quad) * adj_mask[i];
  }
  __syncthreads();
  float* am = ws + OFF_AM + (size_t)b * KC * CH;
  for (int i = t; i < KC * CH; i += TPB) {
    const int p = i >> 7, d = i & 127;
    float a = 0.f;
    for (int q = 0; q < KC; ++q) a += wm[p][q] * ms[q][d];
    am[i] = a;
  }
}

// ---------------------------------------------------------------------------
// K3: analytic BN stats + fused amSB = am*sc + bi. (unchanged)
// ---------------------------------------------------------------------------
__global__ __launch_bounds__(CH) void k3_bn(
    const float* __restrict__ gamma, const float* __restrict__ beta,
    float* __restrict__ ws)
{
  const int d = threadIdx.x;
  float chs = 0.f, cm = 0.f, cam2 = 0.f, cross = 0.f;
  for (int bk = 0; bk < BB * KC; ++bk) {
    const float c = ws[OFF_CNT + bk];
    const float a = ws[OFF_AM + (size_t)bk * CH + d];
    const float s = ws[OFF_SUMS + (size_t)bk * CH + d];
    chs += s; cm += c * a; cam2 += c * a * a; cross += a * s;
  }
  const float N   = (float)BB * (float)HWD;
  const float mu  = (chs + cm) / N;
  const float e2  = (ws[OFF_CHSQ + d] + 2.f * cross + cam2) / N;
  const float var = e2 - mu * mu;
  const float sc  = gamma[d] / sqrtf(var + 1e-5f);
  const float bi  = beta[d] - mu * sc;
  if (blockIdx.x == 0) { ws[OFF_SCALE + d] = sc; ws[OFF_BIAS + d] = bi; }
  for (int r = 0; r < 8; ++r) {
    const int bk = blockIdx.x * 8 + r;
    ws[OFF_AMSB + (size_t)bk * CH + d] = ws[OFF_AM + (size_t)bk * CH + d] * sc + bi;
  }
}

// ---------------------------------------------------------------------------
// K4: recompute xw (bitwise-identical MFMA) from packed xp,
// out = xw*sc + amSB[cls][d]. 4-tile register batching -> each d-row gets
// 1KB of temporally-grouped stores (page-friendly write drain).
// ---------------------------------------------------------------------------
__global__ __launch_bounds__(TPB, 2) void k4_mfma(
    const int* __restrict__ index,
    const float* __restrict__ weight, const float* __restrict__ ws,
    float* __restrict__ out)
{
  __shared__ short xs[2][TILE_BYTES / 2];      // 2 x 16KB packed tile
  __shared__ float amsb[KC][CH + 4];           // 33 KB, stride 132

  const int t = threadIdx.x;
  const int lane = t & 63, lane15 = lane & 15, quad = lane >> 4, w = t >> 6;
  const int mbase = (w & 1) * 64;
  const int nbase = (w >> 1) * 32;
  const int b = blockIdx.x / BLOCKS_PER_B;
  const int px_base = (blockIdx.x % BLOCKS_PER_B) * PX_PER_BLOCK;
  const size_t ti0 = (size_t)b * 1024 + (px_base >> 6);
  const char* xp = (const char*)(ws + OFF_XP);

  const float* ag = ws + OFF_AMSB + (size_t)b * KC * CH;
  for (int i = t; i < KC * CH / 4; i += TPB) {
    const int k = (i * 4) >> 7, dd = (i * 4) & 127;
    *(float4*)&amsb[k][dd] = *(const float4*)&ag[k * CH + dd];
  }

  bf16x8 af[4][4];
  load_w_frags(weight, mbase, lane15, quad, af);

  float scr[4][4];
#pragma unroll
  for (int mt = 0; mt < 4; ++mt)
#pragma unroll
    for (int r = 0; r < 4; ++r)
      scr[mt][r] = ws[OFF_SCALE + mbase + mt * 16 + quad * 4 + r];

  const int* ib = index + (size_t)b * HWD;
  float*     ob = out + (size_t)b * CH * HWD;

  stage_tile(xp + ti0 * TILE_BYTES, &xs[0][0], w, lane);
  __syncthreads();   // covers amsb fill + tile0 DMA

#pragma unroll
  for (int g4 = 0; g4 < 4; ++g4) {
    f32x4 acc[4][4][2] = {};
    int clsv[4][2];
#pragma unroll
    for (int g = 0; g < 4; ++g) {
      const int tile = g4 * 4 + g;
      const int cur = tile & 1;
      if (tile + 1 < TILES_PER_BLOCK)
        stage_tile(xp + (ti0 + tile + 1) * TILE_BYTES, &xs[cur ^ 1][0], w, lane);

      const int pix0 = px_base + tile * TILE;
#pragma unroll
      for (int nt = 0; nt < 2; ++nt)
        clsv[g][nt] = ib[pix0 + nbase + nt * 16 + lane15];

      const char* xt = (const char*)&xs[cur][0];
#pragma unroll
      for (int kc = 0; kc < 4; ++kc) {
        bf16x8 bfr[2];
#pragma unroll
        for (int nt = 0; nt < 2; ++nt)
          bfr[nt] = bfrag(xt, nbase + nt * 16 + lane15, kc, quad);
#pragma unroll
        for (int mt = 0; mt < 4; ++mt)
#pragma unroll
          for (int nt = 0; nt < 2; ++nt)
            acc[g][mt][nt] = __builtin_amdgcn_mfma_f32_16x16x32_bf16(af[mt][kc], bfr[nt], acc[g][mt][nt], 0, 0, 0);
      }
      __syncthreads();
    }

    // flush 4 tiles: per d-row, 8x 64B chunks spanning 256 px, issued together
    const int pxg = px_base + g4 * 256;
#pragma unroll
    for (int mt = 0; mt < 4; ++mt)
#pragma unroll
      for (int r = 0; r < 4; ++r) {
        const int d = mbase + mt * 16 + quad * 4 + r;
        const float sc = scr[mt][r];
        float* obd = ob + (size_t)d * HWD;
#pragma unroll
        for (int g = 0; g < 4; ++g)
#pragma unroll
          for (int nt = 0; nt < 2; ++nt) {
            const int px = pxg + g * 64 + nbase + nt * 16 + lane15;
            obd[px] = acc[g][mt][nt][r] * sc + amsb[clsv[g][nt]][d];
          }
      }
  }
}

extern "C" void kernel_launch(void* const* d_in, const int* in_sizes, int n_in,
                              void* d_out, int out_size, void* d_ws, size_t ws_size,
                              hipStream_t stream) {
  const float* x        = (const float*)d_in[0];
  const int*   index    = (const int*)d_in[1];
  const float* weight   = (const float*)d_in[2];
  const float* Wm       = (const float*)d_in[3];
  const float* adj_mask = (const float*)d_in[4];
  const float* gamma    = (const float*)d_in[5];
  const float* beta     = (const float*)d_in[6];
  float* ws  = (float*)d_ws;
  float* out = (float*)d_out;
  (void)ws_size;  // needs OFF_XP*4 + 134,217,728 B ≈ 135 MB

  // zero the cross-block atomic accumulators (sums, counts, chsq)
  hipMemsetAsync(ws, 0, (size_t)OFF_AM * sizeof(float), stream);

  k0_pack<<<BB * 256, TPB, 0, stream>>>(x, ws);
  k1_mfma<<<BB * BLOCKS_PER_B, TPB, 0, stream>>>(index, weight, ws);
  k2_adj <<<BB, TPB, 0, stream>>>(Wm, adj_mask, ws);
  k3_bn  <<<KC, CH, 0, stream>>>(gamma, beta, ws);
  k4_mfma<<<BB * BLOCKS_PER_B, TPB, 0, stream>>>(index, weight, ws, out);
}